// Round 1
// baseline (517.463 us; speedup 1.0000x reference)
//
#include <hip/hip_runtime.h>
#include <type_traits>

#define DI __device__ __forceinline__

typedef __attribute__((ext_vector_type(8))) __bf16 vbf8;
typedef __attribute__((ext_vector_type(8))) short  vs8;
typedef __attribute__((ext_vector_type(4))) float  f4;

static constexpr int BB   = 2;
static constexpr int C    = 256;
static constexpr int NN   = 4096;   // H*W*D
static constexpr int HID  = 512;
static constexpr int QKVR = 1536;

// ---------- bf16 helpers ----------
static DI unsigned short f2bf(float f) {   // round-to-nearest-even
  unsigned int u = __builtin_bit_cast(unsigned int, f);
  u += 0x7fffu + ((u >> 16) & 1u);
  return (unsigned short)(u >> 16);
}

// ---------- MFMA wrapper robust to builtin signature (v8bf16 vs v8i16) ----------
template <typename V>
static DI auto mfma_sel(V a, V b, f4 c, int)
    -> decltype(__builtin_amdgcn_mfma_f32_16x16x32_bf16(a, b, c, 0, 0, 0)) {
  return __builtin_amdgcn_mfma_f32_16x16x32_bf16(a, b, c, 0, 0, 0);
}
template <typename V>
static DI f4 mfma_sel(V a, V b, f4 c, long) {
  return __builtin_amdgcn_mfma_f32_16x16x32_bf16(
      __builtin_bit_cast(vs8, a), __builtin_bit_cast(vs8, b), c, 0, 0, 0);
}
static DI f4 MFMA(vs8 a, vs8 b, f4 c) {
  return mfma_sel(__builtin_bit_cast(vbf8, a), __builtin_bit_cast(vbf8, b), c, 0);
}

// ---------- K0: cast weights to bf16 (fold g into w_qkv columns) ----------
__global__ void k_prep(const float* __restrict__ wqkv, const float* __restrict__ g,
                       const float* __restrict__ wout,
                       unsigned short* __restrict__ wg, unsigned short* __restrict__ wo) {
  int i = blockIdx.x * 256 + threadIdx.x;
  if (i < QKVR * C) wg[i] = f2bf(wqkv[i] * g[i & (C - 1)]);
  if (i < C * HID)  wo[i] = f2bf(wout[i]);
}

// ---------- K1: per-token channel inv-norm: 16 / max(||x||, 1e-12) ----------
__global__ void k_norm(const float* __restrict__ x, float* __restrict__ invn) {
  int i = blockIdx.x * 256 + threadIdx.x;       // [0, BB*NN)
  int b = i >> 12, n = i & (NN - 1);
  const float* xp = x + (size_t)b * C * NN + n;
  float s = 0.f;
  #pragma unroll 8
  for (int c = 0; c < C; ++c) { float v = xp[(size_t)c * NN]; s += v * v; }
  invn[i] = 16.0f / fmaxf(sqrtf(s), 1e-12f);
}

// ---------- K2: QKV projection GEMM  qkv[o][n] = invn[n]*sum_c wg[o][c]*x[c][n] ----------
// block: 256 thr (4 waves); o-tile 64 (== one head of one of q/k/v), n-tile 64, K=256.
// x-tile staged transposed in LDS as bf16 [64 n][264] (stride 264: 132 words == 4 mod 8 -> b128-optimal).
__global__ __launch_bounds__(256) void k_qkv(const float* __restrict__ x,
    const unsigned short* __restrict__ wg, const float* __restrict__ invn,
    unsigned short* __restrict__ qo, unsigned short* __restrict__ ko,
    unsigned short* __restrict__ vo) {
  __shared__ unsigned short xs[64 * 264];
  const int bo = blockIdx.x % 24;
  const int bn = (blockIdx.x / 24) & 63;
  const int b  = blockIdx.x / (24 * 64);
  const int o0 = bo * 64, n0 = bn * 64;
  const int tid = threadIdx.x;
  {
    const int nl = tid & 63, cb = tid >> 6;
    const float* xp = x + (size_t)b * C * NN + n0 + nl;
    #pragma unroll 4
    for (int kk = 0; kk < 64; ++kk) {
      int c = cb * 64 + kk;
      xs[nl * 264 + c] = f2bf(xp[(size_t)c * NN]);
    }
  }
  __syncthreads();
  const int wave = tid >> 6, lane = tid & 63, lr = lane & 15, lg = lane >> 4;
  const int orow = o0 + wave * 16;
  f4 acc[4] = { {0,0,0,0},{0,0,0,0},{0,0,0,0},{0,0,0,0} };
  const unsigned short* wp = wg + (size_t)(orow + lr) * C + lg * 8;
  #pragma unroll
  for (int c0 = 0; c0 < C; c0 += 32) {
    vs8 af = *(const vs8*)(wp + c0);                       // A[m=lr][k=c0+8lg+i]
    #pragma unroll
    for (int nc = 0; nc < 4; ++nc) {
      vs8 bf = *(const vs8*)(&xs[(nc * 16 + lr) * 264 + c0 + lg * 8]);  // B[k][n=lr]
      acc[nc] = MFMA(af, bf, acc[nc]);
    }
  }
  // epilogue: lane holds out[o = orow+4lg+r][n = n0+16nc+lr]
  const int otype = o0 >> 9;            // 0=q 1=k 2=v
  const int head  = (o0 >> 6) & 7;
  const int bh    = b * 8 + head;
  const int dbase = wave * 16 + lg * 4; // d within head
  #pragma unroll
  for (int nc = 0; nc < 4; ++nc) {
    const int n = n0 + nc * 16 + lr;
    float s = invn[b * NN + n];
    if (otype == 0) s *= 0.125f;        // fold DIM_HEAD^-0.5 into q
    if (otype < 2) {                    // q,k: [bh][n][64]
      unsigned short* dst = (otype == 0 ? qo : ko) + ((size_t)bh * NN + n) * 64 + dbase;
      unsigned long long pk = 0;
      #pragma unroll
      for (int r = 0; r < 4; ++r)
        pk |= (unsigned long long)f2bf(acc[nc][r] * s) << (16 * r);
      *(unsigned long long*)dst = pk;   // 4 consecutive d, 8B aligned
    } else {                            // v transposed: [bh][64][n]
      #pragma unroll
      for (int r = 0; r < 4; ++r)
        vo[((size_t)bh * 64 + dbase + r) * NN + n] = f2bf(acc[nc][r] * s);
    }
  }
}

// ---------- K3: flash attention. 4 waves/block, 16 q-rows/wave, j-chunks of 32 ----------
__global__ __launch_bounds__(256) void k_attn(const unsigned short* __restrict__ qq,
    const unsigned short* __restrict__ kk, const unsigned short* __restrict__ vv,
    unsigned short* __restrict__ ob) {
  __shared__ unsigned short pls[4][16 * 40];   // per-wave P tile, stride 40 (20 words == 4 mod 8)
  // XCD-aware swizzle: give each XCD contiguous work (2 heads' K/V -> 2MB fits its L2)
  const int rawid = blockIdx.x + 64 * blockIdx.y;          // 0..1023
  const int wid   = (rawid & 7) * 128 + (rawid >> 3);
  const int bh    = wid >> 6;
  const int qt    = wid & 63;
  const int tid = threadIdx.x, wave = tid >> 6, lane = tid & 63;
  const int lr = lane & 15, lg = lane >> 4;
  const int qrow = qt * 64 + wave * 16;
  const unsigned short* qp = qq + ((size_t)bh * NN + qrow + lr) * 64 + lg * 8;
  const vs8 qf0 = *(const vs8*)qp;          // Q[m=lr][d=8lg+i]
  const vs8 qf1 = *(const vs8*)(qp + 32);   // d+32
  const unsigned short* kb = kk + (size_t)bh * NN * 64;
  const unsigned short* vb = vv + (size_t)bh * 64 * NN;
  unsigned short* pl = pls[wave];
  f4 oacc[4] = { {0,0,0,0},{0,0,0,0},{0,0,0,0},{0,0,0,0} };
  float m[4] = {-1e30f,-1e30f,-1e30f,-1e30f};
  float l[4] = {0.f,0.f,0.f,0.f};
  for (int j0 = 0; j0 < NN; j0 += 32) {
    // --- S = Q K^T for 16x32 tile pair ---
    const unsigned short* kp = kb + (size_t)(j0 + lr) * 64 + lg * 8;
    vs8 kf0 = *(const vs8*)(kp);            // K[j0+lr][8lg+i]
    vs8 kf1 = *(const vs8*)(kp + 32);
    vs8 kf2 = *(const vs8*)(kp + 1024);     // rows j0+16..j0+31
    vs8 kf3 = *(const vs8*)(kp + 1056);
    f4 s0 = {0,0,0,0}, s1 = {0,0,0,0};
    s0 = MFMA(qf0, kf0, s0);
    s0 = MFMA(qf1, kf1, s0);
    s1 = MFMA(qf0, kf2, s1);
    s1 = MFMA(qf1, kf3, s1);
    // lane holds S[q=4lg+r][j0+lr] (s0) and S[...][j0+16+lr] (s1); scale folded into q.
    float tmax[4], alpha[4], psum[4];
    #pragma unroll
    for (int r = 0; r < 4; ++r) tmax[r] = fmaxf(s0[r], s1[r]);
    #pragma unroll
    for (int off = 8; off; off >>= 1) {
      #pragma unroll
      for (int r = 0; r < 4; ++r) tmax[r] = fmaxf(tmax[r], __shfl_xor(tmax[r], off));
    }
    #pragma unroll
    for (int r = 0; r < 4; ++r) {
      float mn = fmaxf(m[r], tmax[r]);
      alpha[r] = __expf(m[r] - mn);
      float p0 = __expf(s0[r] - mn);
      float p1 = __expf(s1[r] - mn);
      m[r] = mn; s0[r] = p0; s1[r] = p1;
      psum[r] = p0 + p1;
    }
    #pragma unroll
    for (int off = 8; off; off >>= 1) {
      #pragma unroll
      for (int r = 0; r < 4; ++r) psum[r] += __shfl_xor(psum[r], off);
    }
    #pragma unroll
    for (int r = 0; r < 4; ++r) l[r] = l[r] * alpha[r] + psum[r];
    #pragma unroll
    for (int dc = 0; dc < 4; ++dc) {
      #pragma unroll
      for (int r = 0; r < 4; ++r) oacc[dc][r] *= alpha[r];
    }
    // --- P (bf16) through per-wave LDS: [q-row][j-local], stride 40 ---
    #pragma unroll
    for (int r = 0; r < 4; ++r) {
      pl[(lg * 4 + r) * 40 + lr]      = f2bf(s0[r]);
      pl[(lg * 4 + r) * 40 + 16 + lr] = f2bf(s1[r]);
    }
    asm volatile("s_waitcnt lgkmcnt(0)" ::: "memory");  // wave-local write->read fence
    vs8 pa = *(const vs8*)(pl + lr * 40 + lg * 8);      // P[m=lr][k=8lg+i]
    #pragma unroll
    for (int dc = 0; dc < 4; ++dc) {
      vs8 vf = *(const vs8*)(vb + (size_t)(dc * 16 + lr) * NN + j0 + lg * 8); // V^T row
      oacc[dc] = MFMA(pa, vf, oacc[dc]);
    }
  }
  // epilogue: O[q][d]/l -> obuf[b][h*64+d][n] bf16
  const int b = bh >> 3, h = bh & 7;
  float rl[4];
  #pragma unroll
  for (int r = 0; r < 4; ++r) rl[r] = 1.0f / l[r];
  #pragma unroll
  for (int dc = 0; dc < 4; ++dc) {
    #pragma unroll
    for (int r = 0; r < 4; ++r)
      ob[(size_t)(b * HID + h * 64 + dc * 16 + lr) * NN + qrow + lg * 4 + r] =
          f2bf(oacc[dc][r] * rl[r]);
  }
}

// ---------- K4: out projection y = w_out @ O + b ----------
__global__ __launch_bounds__(256) void k_out(const unsigned short* __restrict__ obuf,
    const unsigned short* __restrict__ wo, const float* __restrict__ bout,
    float* __restrict__ y) {
  __shared__ unsigned short os[64 * 136];   // [n 64][c-chunk 128], stride 136 (68 words == 4 mod 8)
  const int bo = blockIdx.x & 3;
  const int bn = (blockIdx.x >> 2) & 63;
  const int b  = blockIdx.x >> 8;
  const int o0 = bo * 64, n0 = bn * 64;
  const int tid = threadIdx.x, wave = tid >> 6, lane = tid & 63, lr = lane & 15, lg = lane >> 4;
  const int orow = o0 + wave * 16;
  f4 acc[4] = { {0,0,0,0},{0,0,0,0},{0,0,0,0},{0,0,0,0} };
  for (int c0 = 0; c0 < HID; c0 += 128) {
    __syncthreads();
    {
      const int nl = tid & 63, cb = tid >> 6;
      const unsigned short* sp = obuf + ((size_t)b * HID + c0) * NN + n0 + nl;
      #pragma unroll 4
      for (int t = 0; t < 32; ++t) {
        int cc = cb * 32 + t;
        os[nl * 136 + cc] = sp[(size_t)cc * NN];
      }
    }
    __syncthreads();
    const unsigned short* wp = wo + (size_t)(orow + lr) * HID + c0 + lg * 8;
    #pragma unroll
    for (int cc0 = 0; cc0 < 128; cc0 += 32) {
      vs8 af = *(const vs8*)(wp + cc0);
      #pragma unroll
      for (int nc = 0; nc < 4; ++nc) {
        vs8 bf = *(const vs8*)(&os[(nc * 16 + lr) * 136 + cc0 + lg * 8]);
        acc[nc] = MFMA(af, bf, acc[nc]);
      }
    }
  }
  #pragma unroll
  for (int nc = 0; nc < 4; ++nc) {
    const int n = n0 + nc * 16 + lr;
    #pragma unroll
    for (int r = 0; r < 4; ++r)
      y[((size_t)b * C + orow + lg * 4 + r) * NN + n] = acc[nc][r] + bout[orow + lg * 4 + r];
  }
}

extern "C" void kernel_launch(void* const* d_in, const int* in_sizes, int n_in,
                              void* d_out, int out_size, void* d_ws, size_t ws_size,
                              hipStream_t stream) {
  const float* x    = (const float*)d_in[0];
  const float* g    = (const float*)d_in[1];
  const float* wqkv = (const float*)d_in[2];
  const float* wout = (const float*)d_in[3];
  const float* bout = (const float*)d_in[4];
  float* y = (float*)d_out;
  char* ws = (char*)d_ws;
  // workspace layout (34.6 MB total)
  unsigned short* wg   = (unsigned short*)(ws);                          // 786432 B
  unsigned short* wo   = (unsigned short*)(ws + 786432);                 // 262144 B
  float*          invn = (float*)(ws + 1048576);                         // 32768 B
  unsigned short* qb   = (unsigned short*)(ws + 1081344);                // 8 MB [bh][n][64]
  unsigned short* kb   = (unsigned short*)(ws + 1081344 + 8388608);      // 8 MB [bh][n][64]
  unsigned short* vtb  = (unsigned short*)(ws + 1081344 + 2 * 8388608);  // 8 MB [bh][64][n]
  unsigned short* obuf = (unsigned short*)(ws + 1081344 + 3 * 8388608);  // 8 MB [b][512][n]
  k_prep<<<1536, 256, 0, stream>>>(wqkv, g, wout, wg, wo);
  k_norm<<<32, 256, 0, stream>>>(x, invn);
  k_qkv<<<3072, 256, 0, stream>>>(x, wg, invn, qb, kb, vtb);
  k_attn<<<dim3(64, 16), 256, 0, stream>>>(qb, kb, vtb, obuf);
  k_out<<<512, 256, 0, stream>>>(obuf, wo, bout, y);
}

// Round 2
// 196.462 us; speedup vs baseline: 2.6339x; 2.6339x over previous
//
#include <hip/hip_runtime.h>
#include <type_traits>

#define DI __device__ __forceinline__

typedef __attribute__((ext_vector_type(8))) __bf16 vbf8;
typedef __attribute__((ext_vector_type(8))) short  vs8;
typedef __attribute__((ext_vector_type(4))) float  f4;

static constexpr int BB   = 2;
static constexpr int C    = 256;
static constexpr int NN   = 4096;   // H*W*D
static constexpr int HID  = 512;
static constexpr int QKVR = 1536;

// ---------- bf16 helpers ----------
static DI unsigned short f2bf(float f) {   // round-to-nearest-even
  unsigned int u = __builtin_bit_cast(unsigned int, f);
  u += 0x7fffu + ((u >> 16) & 1u);
  return (unsigned short)(u >> 16);
}
static DI unsigned int cvtpk(float lo, float hi) {  // 2xf32 -> packed bf16 (lo in low half)
  unsigned int r;
  asm("v_cvt_pk_bf16_f32 %0, %1, %2" : "=v"(r) : "v"(lo), "v"(hi));
  return r;
}
static DI float EXP2(float x) {
#if __has_builtin(__builtin_amdgcn_exp2f)
  return __builtin_amdgcn_exp2f(x);
#else
  return exp2f(x);
#endif
}

// ---------- MFMA wrapper robust to builtin signature (v8bf16 vs v8i16) ----------
template <typename V>
static DI auto mfma_sel(V a, V b, f4 c, int)
    -> decltype(__builtin_amdgcn_mfma_f32_16x16x32_bf16(a, b, c, 0, 0, 0)) {
  return __builtin_amdgcn_mfma_f32_16x16x32_bf16(a, b, c, 0, 0, 0);
}
template <typename V>
static DI f4 mfma_sel(V a, V b, f4 c, long) {
  return __builtin_amdgcn_mfma_f32_16x16x32_bf16(
      __builtin_bit_cast(vs8, a), __builtin_bit_cast(vs8, b), c, 0, 0, 0);
}
static DI f4 MFMA(vs8 a, vs8 b, f4 c) {
  return mfma_sel(__builtin_bit_cast(vbf8, a), __builtin_bit_cast(vbf8, b), c, 0);
}

// ---------- async global->LDS, 16B per lane ----------
static DI void gll16(const unsigned short* g, unsigned short* l) {
  __builtin_amdgcn_global_load_lds(
      (const __attribute__((address_space(1))) unsigned int*)g,
      (__attribute__((address_space(3))) unsigned int*)l, 16, 0, 0);
}

// ---------- K0: cast weights to bf16 (fold g into w_qkv columns) ----------
__global__ void k_prep(const float* __restrict__ wqkv, const float* __restrict__ g,
                       const float* __restrict__ wout,
                       unsigned short* __restrict__ wg, unsigned short* __restrict__ wo) {
  int i = blockIdx.x * 256 + threadIdx.x;
  if (i < QKVR * C) wg[i] = f2bf(wqkv[i] * g[i & (C - 1)]);
  if (i < C * HID)  wo[i] = f2bf(wout[i]);
}

// ---------- K1: per-token channel inv-norm: 16 / max(||x||, 1e-12) ----------
__global__ void k_norm(const float* __restrict__ x, float* __restrict__ invn) {
  int i = blockIdx.x * 256 + threadIdx.x;       // [0, BB*NN)
  int b = i >> 12, n = i & (NN - 1);
  const float* xp = x + (size_t)b * C * NN + n;
  float s = 0.f;
  #pragma unroll 8
  for (int c = 0; c < C; ++c) { float v = xp[(size_t)c * NN]; s += v * v; }
  invn[i] = 16.0f / fmaxf(sqrtf(s), 1e-12f);
}

// ---------- K2: QKV projection GEMM ----------
__global__ __launch_bounds__(256) void k_qkv(const float* __restrict__ x,
    const unsigned short* __restrict__ wg, const float* __restrict__ invn,
    unsigned short* __restrict__ qo, unsigned short* __restrict__ ko,
    unsigned short* __restrict__ vo) {
  __shared__ unsigned short xs[64 * 264];
  const int bo = blockIdx.x % 24;
  const int bn = (blockIdx.x / 24) & 63;
  const int b  = blockIdx.x / (24 * 64);
  const int o0 = bo * 64, n0 = bn * 64;
  const int tid = threadIdx.x;
  {
    const int nl = tid & 63, cb = tid >> 6;
    const float* xp = x + (size_t)b * C * NN + n0 + nl;
    #pragma unroll 4
    for (int kk = 0; kk < 64; ++kk) {
      int c = cb * 64 + kk;
      xs[nl * 264 + c] = f2bf(xp[(size_t)c * NN]);
    }
  }
  __syncthreads();
  const int wave = tid >> 6, lane = tid & 63, lr = lane & 15, lg = lane >> 4;
  const int orow = o0 + wave * 16;
  f4 acc[4] = { {0,0,0,0},{0,0,0,0},{0,0,0,0},{0,0,0,0} };
  const unsigned short* wp = wg + (size_t)(orow + lr) * C + lg * 8;
  #pragma unroll
  for (int c0 = 0; c0 < C; c0 += 32) {
    vs8 af = *(const vs8*)(wp + c0);
    #pragma unroll
    for (int nc = 0; nc < 4; ++nc) {
      vs8 bf = *(const vs8*)(&xs[(nc * 16 + lr) * 264 + c0 + lg * 8]);
      acc[nc] = MFMA(af, bf, acc[nc]);
    }
  }
  const int otype = o0 >> 9;            // 0=q 1=k 2=v
  const int head  = (o0 >> 6) & 7;
  const int bh    = b * 8 + head;
  const int dbase = wave * 16 + lg * 4; // d within head
  #pragma unroll
  for (int nc = 0; nc < 4; ++nc) {
    const int n = n0 + nc * 16 + lr;
    float s = invn[b * NN + n];
    if (otype == 0) s *= 0.125f * 1.44269504088896f; // fold dh^-0.5 and log2(e): softmax in exp2 domain
    if (otype < 2) {                    // q,k: [bh][n][64]
      unsigned short* dst = (otype == 0 ? qo : ko) + ((size_t)bh * NN + n) * 64 + dbase;
      unsigned long long pk = 0;
      #pragma unroll
      for (int r = 0; r < 4; ++r)
        pk |= (unsigned long long)f2bf(acc[nc][r] * s) << (16 * r);
      *(unsigned long long*)dst = pk;
    } else {                            // v transposed: [bh][64][n]
      #pragma unroll
      for (int r = 0; r < 4; ++r)
        vo[((size_t)bh * 64 + dbase + r) * NN + n] = f2bf(acc[nc][r] * s);
    }
  }
}

// ---------- K3: flash attention, v2 ----------
// 4 waves/block, 32 q-rows/wave (128 q/block), KVBLK=64, double-buffered LDS staging.
// Swapped QK^T: S^T = MFMA(K,Q) -> lane holds 16 j for ONE q (q=lr). PV: O^T = MFMA(V^T, P).
// K/V tiles staged fragment-major: ds_read_b128 at base+lane*16 -> conflict-free.
__global__ __launch_bounds__(256) void k_attn(const unsigned short* __restrict__ qq,
    const unsigned short* __restrict__ kk, const unsigned short* __restrict__ vv,
    unsigned short* __restrict__ ob) {
  __shared__ unsigned short stg[2][8192];      // [buf][ K 8 frag-groups *512 | V 8 frag-groups *512 ]
  __shared__ unsigned short pls[4][32 * 72];   // per-wave P tile [32 q][64 j], stride 72
  const int bid = blockIdx.x;
  const int swz = (bid & 7) * 64 + (bid >> 3); // XCD-aware, bijective (512 % 8 == 0)
  const int bh  = swz >> 5;
  const int qt  = swz & 31;
  const int tid = threadIdx.x, wave = tid >> 6, lane = tid & 63;
  const int lr = lane & 15, lg = lane >> 4;
  const int qbase = qt * 128 + wave * 32;
  const unsigned short* kb = kk + (size_t)bh * NN * 64;   // [n][64]
  const unsigned short* vb = vv + (size_t)bh * 64 * NN;   // [64][n]
  // Q fragments (B-operand): qf[qn][kd] = Q[q=qbase+qn*16+lr][d=kd*32+lg*8+i]
  vs8 qf[2][2];
  #pragma unroll
  for (int qn = 0; qn < 2; ++qn)
    #pragma unroll
    for (int kd = 0; kd < 2; ++kd)
      qf[qn][kd] = *(const vs8*)(qq + ((size_t)bh * NN + qbase + qn * 16 + lr) * 64 + kd * 32 + lg * 8);
  unsigned short* pl = pls[wave];
  f4 oacc[4][2] = { { {0,0,0,0},{0,0,0,0} }, { {0,0,0,0},{0,0,0,0} },
                    { {0,0,0,0},{0,0,0,0} }, { {0,0,0,0},{0,0,0,0} } };
  float m[2] = {-1e30f, -1e30f}, l[2] = {0.f, 0.f};

  // staging: wave handles frag-groups {2*wave, 2*wave+1} of K and of V
  auto stage = [&](int j0, int buf) {
    #pragma unroll
    for (int p = 0; p < 2; ++p) {
      const int g  = wave * 2 + p;
      const int jt = g >> 1, kd = g & 1;     // K group: rows j=jt*16+lr, d-half kd
      gll16(kb + (size_t)(j0 + jt * 16 + lr) * 64 + kd * 32 + lg * 8,
            &stg[buf][g * 512]);
      const int dt = g >> 1, kj = g & 1;     // V group: rows d=dt*16+lr, j-half kj
      gll16(vb + (size_t)(dt * 16 + lr) * NN + j0 + kj * 32 + lg * 8,
            &stg[buf][4096 + g * 512]);
    }
  };

  stage(0, 0);
  asm volatile("s_waitcnt vmcnt(0)");
  __syncthreads();

  for (int t = 0; t < NN / 64; ++t) {
    const int cur = t & 1;
    if (t + 1 < NN / 64) stage((t + 1) * 64, cur ^ 1);
    const unsigned short* sbk = stg[cur];
    const unsigned short* sbv = stg[cur] + 4096;
    // --- S^T = K Q^T : s[jt][qn], lane holds S[j=jt*16+4lg+r][q=qn*16+lr] ---
    f4 s[4][2] = { { {0,0,0,0},{0,0,0,0} }, { {0,0,0,0},{0,0,0,0} },
                   { {0,0,0,0},{0,0,0,0} }, { {0,0,0,0},{0,0,0,0} } };
    __builtin_amdgcn_s_setprio(1);
    #pragma unroll
    for (int jt = 0; jt < 4; ++jt) {
      vs8 k0 = *(const vs8*)(sbk + (jt * 2 + 0) * 512 + lane * 8);
      vs8 k1 = *(const vs8*)(sbk + (jt * 2 + 1) * 512 + lane * 8);
      #pragma unroll
      for (int qn = 0; qn < 2; ++qn) {
        s[jt][qn] = MFMA(k0, qf[qn][0], s[jt][qn]);
        s[jt][qn] = MFMA(k1, qf[qn][1], s[jt][qn]);
      }
    }
    __builtin_amdgcn_s_setprio(0);
    // --- online softmax (exp2 domain; scale folded into q) ---
    float alpha[2];
    #pragma unroll
    for (int qn = 0; qn < 2; ++qn) {
      float tm = s[0][qn][0];
      #pragma unroll
      for (int jt = 0; jt < 4; ++jt)
        #pragma unroll
        for (int r = 0; r < 4; ++r)
          if (jt | r) tm = fmaxf(tm, s[jt][qn][r]);
      tm = fmaxf(tm, __shfl_xor(tm, 16));
      tm = fmaxf(tm, __shfl_xor(tm, 32));
      float mn = fmaxf(m[qn], tm);
      float a  = EXP2(m[qn] - mn);
      float ps = 0.f;
      #pragma unroll
      for (int jt = 0; jt < 4; ++jt)
        #pragma unroll
        for (int r = 0; r < 4; ++r) {
          float p = EXP2(s[jt][qn][r] - mn);
          s[jt][qn][r] = p;
          ps += p;
        }
      ps += __shfl_xor(ps, 16);
      ps += __shfl_xor(ps, 32);
      m[qn] = mn;
      l[qn] = l[qn] * a + ps;
      alpha[qn] = a;
    }
    #pragma unroll
    for (int mt = 0; mt < 4; ++mt)
      #pragma unroll
      for (int qn = 0; qn < 2; ++qn)
        #pragma unroll
        for (int r = 0; r < 4; ++r)
          oacc[mt][qn][r] *= alpha[qn];
    // --- P -> per-wave LDS [q][j] (b64 writes of 4 adjacent j) ---
    #pragma unroll
    for (int qn = 0; qn < 2; ++qn)
      #pragma unroll
      for (int jt = 0; jt < 4; ++jt) {
        unsigned int w0 = cvtpk(s[jt][qn][0], s[jt][qn][1]);
        unsigned int w1 = cvtpk(s[jt][qn][2], s[jt][qn][3]);
        *(unsigned long long*)(pl + (qn * 16 + lr) * 72 + jt * 16 + lg * 4) =
            ((unsigned long long)w1 << 32) | w0;
      }
    asm volatile("s_waitcnt lgkmcnt(0)" ::: "memory");  // wave-local write->read fence
    // --- O^T += V^T P : A=V^T[d=lr][j=8lg+i], B=P[q=lr][j=8lg+i] ---
    __builtin_amdgcn_s_setprio(1);
    #pragma unroll
    for (int kj = 0; kj < 2; ++kj) {
      vs8 pb0 = *(const vs8*)(pl + (0 * 16 + lr) * 72 + kj * 32 + lg * 8);
      vs8 pb1 = *(const vs8*)(pl + (1 * 16 + lr) * 72 + kj * 32 + lg * 8);
      #pragma unroll
      for (int mt = 0; mt < 4; ++mt) {
        vs8 vf = *(const vs8*)(sbv + (mt * 2 + kj) * 512 + lane * 8);
        oacc[mt][0] = MFMA(vf, pb0, oacc[mt][0]);
        oacc[mt][1] = MFMA(vf, pb1, oacc[mt][1]);
      }
    }
    __builtin_amdgcn_s_setprio(0);
    asm volatile("s_waitcnt vmcnt(0)");  // staged next-chunk loads have landed
    __syncthreads();
  }
  // --- epilogue: O^T[d][q] / l -> obuf[b][h*64+d][q] bf16 ---
  const int b = bh >> 3, h = bh & 7;
  float rl[2] = {1.0f / l[0], 1.0f / l[1]};
  #pragma unroll
  for (int mt = 0; mt < 4; ++mt)
    #pragma unroll
    for (int qn = 0; qn < 2; ++qn)
      #pragma unroll
      for (int r = 0; r < 4; ++r) {
        int d = mt * 16 + lg * 4 + r;
        int q = qbase + qn * 16 + lr;
        ob[((size_t)(b * HID + h * 64 + d)) * NN + q] = f2bf(oacc[mt][qn][r] * rl[qn]);
      }
}

// ---------- K4: out projection y = w_out @ O + b ----------
__global__ __launch_bounds__(256) void k_out(const unsigned short* __restrict__ obuf,
    const unsigned short* __restrict__ wo, const float* __restrict__ bout,
    float* __restrict__ y) {
  __shared__ unsigned short os[64 * 136];
  const int bo = blockIdx.x & 3;
  const int bn = (blockIdx.x >> 2) & 63;
  const int b  = blockIdx.x >> 8;
  const int o0 = bo * 64, n0 = bn * 64;
  const int tid = threadIdx.x, wave = tid >> 6, lane = tid & 63, lr = lane & 15, lg = lane >> 4;
  const int orow = o0 + wave * 16;
  f4 acc[4] = { {0,0,0,0},{0,0,0,0},{0,0,0,0},{0,0,0,0} };
  for (int c0 = 0; c0 < HID; c0 += 128) {
    __syncthreads();
    {
      const int nl = tid & 63, cb = tid >> 6;
      const unsigned short* sp = obuf + ((size_t)b * HID + c0) * NN + n0 + nl;
      #pragma unroll 4
      for (int t = 0; t < 32; ++t) {
        int cc = cb * 32 + t;
        os[nl * 136 + cc] = sp[(size_t)cc * NN];
      }
    }
    __syncthreads();
    const unsigned short* wp = wo + (size_t)(orow + lr) * HID + c0 + lg * 8;
    #pragma unroll
    for (int cc0 = 0; cc0 < 128; cc0 += 32) {
      vs8 af = *(const vs8*)(wp + cc0);
      #pragma unroll
      for (int nc = 0; nc < 4; ++nc) {
        vs8 bf = *(const vs8*)(&os[(nc * 16 + lr) * 136 + cc0 + lg * 8]);
        acc[nc] = MFMA(af, bf, acc[nc]);
      }
    }
  }
  #pragma unroll
  for (int nc = 0; nc < 4; ++nc) {
    const int n = n0 + nc * 16 + lr;
    #pragma unroll
    for (int r = 0; r < 4; ++r)
      y[((size_t)b * C + orow + lg * 4 + r) * NN + n] = acc[nc][r] + bout[orow + lg * 4 + r];
  }
}

extern "C" void kernel_launch(void* const* d_in, const int* in_sizes, int n_in,
                              void* d_out, int out_size, void* d_ws, size_t ws_size,
                              hipStream_t stream) {
  const float* x    = (const float*)d_in[0];
  const float* g    = (const float*)d_in[1];
  const float* wqkv = (const float*)d_in[2];
  const float* wout = (const float*)d_in[3];
  const float* bout = (const float*)d_in[4];
  float* y = (float*)d_out;
  char* ws = (char*)d_ws;
  unsigned short* wg   = (unsigned short*)(ws);
  unsigned short* wo   = (unsigned short*)(ws + 786432);
  float*          invn = (float*)(ws + 1048576);
  unsigned short* qb   = (unsigned short*)(ws + 1081344);                // [bh][n][64]
  unsigned short* kb   = (unsigned short*)(ws + 1081344 + 8388608);      // [bh][n][64]
  unsigned short* vtb  = (unsigned short*)(ws + 1081344 + 2 * 8388608);  // [bh][64][n]
  unsigned short* obuf = (unsigned short*)(ws + 1081344 + 3 * 8388608);  // [b][512][n]
  k_prep<<<1536, 256, 0, stream>>>(wqkv, g, wout, wg, wo);
  k_norm<<<32, 256, 0, stream>>>(x, invn);
  k_qkv<<<3072, 256, 0, stream>>>(x, wg, invn, qb, kb, vtb);
  k_attn<<<512, 256, 0, stream>>>(qb, kb, vtb, obuf);
  k_out<<<512, 256, 0, stream>>>(obuf, wo, bout, y);
}

// Round 3
// 166.180 us; speedup vs baseline: 3.1139x; 1.1822x over previous
//
#include <hip/hip_runtime.h>
#include <type_traits>

#define DI __device__ __forceinline__

typedef __attribute__((ext_vector_type(8))) __bf16 vbf8;
typedef __attribute__((ext_vector_type(8))) short  vs8;
typedef __attribute__((ext_vector_type(4))) float  f4;
typedef __attribute__((ext_vector_type(4))) unsigned int u32x4;

static constexpr int BB   = 2;
static constexpr int C    = 256;
static constexpr int NN   = 4096;   // H*W*D
static constexpr int HID  = 512;
static constexpr int QKVR = 1536;

// ---------- bf16 helpers ----------
static DI unsigned short f2bf(float f) {   // round-to-nearest-even
  unsigned int u = __builtin_bit_cast(unsigned int, f);
  u += 0x7fffu + ((u >> 16) & 1u);
  return (unsigned short)(u >> 16);
}
static DI unsigned int cvtpk(float lo, float hi) {  // 2xf32 -> packed bf16 (lo in low half)
  unsigned int r;
  asm("v_cvt_pk_bf16_f32 %0, %1, %2" : "=v"(r) : "v"(lo), "v"(hi));
  return r;
}
static DI float EXP2(float x) {
#if __has_builtin(__builtin_amdgcn_exp2f)
  return __builtin_amdgcn_exp2f(x);
#else
  return exp2f(x);
#endif
}
// permlane swaps (gfx950): a' = {a.g0,b.g0,a.g2,b.g2}/{a.lo32,b.lo32}, b' gets the rest
static DI void swap16(unsigned int &a, unsigned int &b) {
  asm("v_permlane16_swap_b32 %0, %1" : "+v"(a), "+v"(b));
}
static DI void swap32(unsigned int &a, unsigned int &b) {
  asm("v_permlane32_swap_b32 %0, %1" : "+v"(a), "+v"(b));
}

// ---------- MFMA wrapper robust to builtin signature (v8bf16 vs v8i16) ----------
template <typename V>
static DI auto mfma_sel(V a, V b, f4 c, int)
    -> decltype(__builtin_amdgcn_mfma_f32_16x16x32_bf16(a, b, c, 0, 0, 0)) {
  return __builtin_amdgcn_mfma_f32_16x16x32_bf16(a, b, c, 0, 0, 0);
}
template <typename V>
static DI f4 mfma_sel(V a, V b, f4 c, long) {
  return __builtin_amdgcn_mfma_f32_16x16x32_bf16(
      __builtin_bit_cast(vs8, a), __builtin_bit_cast(vs8, b), c, 0, 0, 0);
}
static DI f4 MFMA(vs8 a, vs8 b, f4 c) {
  return mfma_sel(__builtin_bit_cast(vbf8, a), __builtin_bit_cast(vbf8, b), c, 0);
}

// ---------- async global->LDS, 16B per lane ----------
static DI void gll16(const unsigned short* g, unsigned short* l) {
  __builtin_amdgcn_global_load_lds(
      (const __attribute__((address_space(1))) unsigned int*)g,
      (__attribute__((address_space(3))) unsigned int*)l, 16, 0, 0);
}

// ---------- K0: cast weights to bf16 (fold g into w_qkv columns) ----------
__global__ void k_prep(const float* __restrict__ wqkv, const float* __restrict__ g,
                       const float* __restrict__ wout,
                       unsigned short* __restrict__ wg, unsigned short* __restrict__ wo) {
  int i = blockIdx.x * 256 + threadIdx.x;
  if (i < QKVR * C) wg[i] = f2bf(wqkv[i] * g[i & (C - 1)]);
  if (i < C * HID)  wo[i] = f2bf(wout[i]);
}

// ---------- K1: per-token channel inv-norm: 16 / max(||x||, 1e-12) ----------
__global__ void k_norm(const float* __restrict__ x, float* __restrict__ invn) {
  int i = blockIdx.x * 256 + threadIdx.x;       // [0, BB*NN)
  int b = i >> 12, n = i & (NN - 1);
  const float* xp = x + (size_t)b * C * NN + n;
  float s = 0.f;
  #pragma unroll 8
  for (int c = 0; c < C; ++c) { float v = xp[(size_t)c * NN]; s += v * v; }
  invn[i] = 16.0f / fmaxf(sqrtf(s), 1e-12f);
}

// ---------- K2: QKV projection GEMM (o-tile 128, n-tile 64) ----------
__global__ __launch_bounds__(256) void k_qkv(const float* __restrict__ x,
    const unsigned short* __restrict__ wg, const float* __restrict__ invn,
    unsigned short* __restrict__ qo, unsigned short* __restrict__ ko,
    unsigned short* __restrict__ vo) {
  __shared__ unsigned short xs[64 * 264];
  const int bo = blockIdx.x % 12;
  const int bn = (blockIdx.x / 12) & 63;
  const int b  = blockIdx.x / (12 * 64);
  const int o0 = bo * 128, n0 = bn * 64;
  const int tid = threadIdx.x;
  {
    const int nl = tid & 63, cb = tid >> 6;
    const float* xp = x + (size_t)b * C * NN + n0 + nl;
    #pragma unroll 4
    for (int kk = 0; kk < 64; ++kk) {
      int c = cb * 64 + kk;
      xs[nl * 264 + c] = f2bf(xp[(size_t)c * NN]);
    }
  }
  __syncthreads();
  const int wave = tid >> 6, lane = tid & 63, lr = lane & 15, lg = lane >> 4;
  const int orow = o0 + wave * 32;
  f4 acc[2][4] = { { {0,0,0,0},{0,0,0,0},{0,0,0,0},{0,0,0,0} },
                   { {0,0,0,0},{0,0,0,0},{0,0,0,0},{0,0,0,0} } };
  const unsigned short* wp0 = wg + (size_t)(orow + lr) * C + lg * 8;
  const unsigned short* wp1 = wg + (size_t)(orow + 16 + lr) * C + lg * 8;
  #pragma unroll
  for (int c0 = 0; c0 < C; c0 += 32) {
    vs8 af0 = *(const vs8*)(wp0 + c0);
    vs8 af1 = *(const vs8*)(wp1 + c0);
    #pragma unroll
    for (int nc = 0; nc < 4; ++nc) {
      vs8 bf = *(const vs8*)(&xs[(nc * 16 + lr) * 264 + c0 + lg * 8]);
      acc[0][nc] = MFMA(af0, bf, acc[0][nc]);
      acc[1][nc] = MFMA(af1, bf, acc[1][nc]);
    }
  }
  #pragma unroll
  for (int om = 0; om < 2; ++om) {
    const int om_row = orow + om * 16;
    const int otype = om_row >> 9;        // 0=q 1=k 2=v
    const int head  = (om_row >> 6) & 7;
    const int bh    = b * 8 + head;
    const int dbase = (om_row & 63) + lg * 4;
    #pragma unroll
    for (int nc = 0; nc < 4; ++nc) {
      const int n = n0 + nc * 16 + lr;
      float s = invn[b * NN + n];
      if (otype == 0) s *= 0.125f * 1.44269504088896f; // fold dh^-0.5 and log2(e)
      if (otype < 2) {                    // q,k: [bh][n][64]
        unsigned short* dst = (otype == 0 ? qo : ko) + ((size_t)bh * NN + n) * 64 + dbase;
        unsigned long long pk = 0;
        #pragma unroll
        for (int r = 0; r < 4; ++r)
          pk |= (unsigned long long)f2bf(acc[om][nc][r] * s) << (16 * r);
        *(unsigned long long*)dst = pk;
      } else {                            // v transposed: [bh][64][n]
        #pragma unroll
        for (int r = 0; r < 4; ++r)
          vo[((size_t)bh * 64 + dbase + r) * NN + n] = f2bf(acc[om][nc][r] * s);
      }
    }
  }
}

// ---------- K3: flash attention, v3 ----------
// 4 waves/block, 32 q/wave, KVBLK=64, double-buffered LDS K/V staging (fragment-major).
// Swapped QK^T; softmax with defer-max (THR=8, exp2 domain) and per-lane deferred l;
// P->B-fragment redistribution fully in-register via permlane{32,16}_swap.
__global__ __launch_bounds__(256) void k_attn(const unsigned short* __restrict__ qq,
    const unsigned short* __restrict__ kk, const unsigned short* __restrict__ vv,
    unsigned short* __restrict__ ob) {
  __shared__ unsigned short stg[2][8192];      // [buf][ K 8 groups*512 | V 8 groups*512 ]
  const int bid = blockIdx.x;
  const int swz = (bid & 7) * 64 + (bid >> 3); // XCD-aware, bijective (512 % 8 == 0)
  const int bh  = swz >> 5;
  const int qt  = swz & 31;
  const int tid = threadIdx.x, wave = tid >> 6, lane = tid & 63;
  const int lr = lane & 15, lg = lane >> 4;
  const int qbase = qt * 128 + wave * 32;
  const unsigned short* kb = kk + (size_t)bh * NN * 64;   // [n][64]
  const unsigned short* vb = vv + (size_t)bh * 64 * NN;   // [64][n]
  vs8 qf[2][2];
  #pragma unroll
  for (int qn = 0; qn < 2; ++qn)
    #pragma unroll
    for (int kd = 0; kd < 2; ++kd)
      qf[qn][kd] = *(const vs8*)(qq + ((size_t)bh * NN + qbase + qn * 16 + lr) * 64 + kd * 32 + lg * 8);
  f4 oacc[4][2] = { { {0,0,0,0},{0,0,0,0} }, { {0,0,0,0},{0,0,0,0} },
                    { {0,0,0,0},{0,0,0,0} }, { {0,0,0,0},{0,0,0,0} } };
  float m[2] = {-1e30f, -1e30f}, lp[2] = {0.f, 0.f};

  auto stage = [&](int j0, int buf) {
    #pragma unroll
    for (int p = 0; p < 2; ++p) {
      const int g  = wave * 2 + p;
      const int jt = g >> 1, kd = g & 1;     // K group
      gll16(kb + (size_t)(j0 + jt * 16 + lr) * 64 + kd * 32 + lg * 8,
            &stg[buf][g * 512]);
      const int dt = g >> 1, kj = g & 1;     // V group
      gll16(vb + (size_t)(dt * 16 + lr) * NN + j0 + kj * 32 + lg * 8,
            &stg[buf][4096 + g * 512]);
    }
  };

  stage(0, 0);
  asm volatile("s_waitcnt vmcnt(0)");
  __syncthreads();

  for (int t = 0; t < NN / 64; ++t) {
    const int cur = t & 1;
    if (t + 1 < NN / 64) stage((t + 1) * 64, cur ^ 1);
    const unsigned short* sbk = stg[cur];
    const unsigned short* sbv = stg[cur] + 4096;
    // --- S^T = K Q^T : lane holds S[j=jt*16+4lg+r][q=qn*16+lr] ---
    f4 s[4][2] = { { {0,0,0,0},{0,0,0,0} }, { {0,0,0,0},{0,0,0,0} },
                   { {0,0,0,0},{0,0,0,0} }, { {0,0,0,0},{0,0,0,0} } };
    __builtin_amdgcn_s_setprio(1);
    #pragma unroll
    for (int jt = 0; jt < 4; ++jt) {
      vs8 k0 = *(const vs8*)(sbk + (jt * 2 + 0) * 512 + lane * 8);
      vs8 k1 = *(const vs8*)(sbk + (jt * 2 + 1) * 512 + lane * 8);
      #pragma unroll
      for (int qn = 0; qn < 2; ++qn) {
        s[jt][qn] = MFMA(k0, qf[qn][0], s[jt][qn]);
        s[jt][qn] = MFMA(k1, qf[qn][1], s[jt][qn]);
      }
    }
    __builtin_amdgcn_s_setprio(0);
    // --- defer-max online softmax (exp2 domain; scale folded into q) ---
    float pm[2];
    #pragma unroll
    for (int qn = 0; qn < 2; ++qn) {
      float a0 = fmaxf(fmaxf(s[0][qn][0], s[0][qn][1]), fmaxf(s[0][qn][2], s[0][qn][3]));
      float a1 = fmaxf(fmaxf(s[1][qn][0], s[1][qn][1]), fmaxf(s[1][qn][2], s[1][qn][3]));
      float a2 = fmaxf(fmaxf(s[2][qn][0], s[2][qn][1]), fmaxf(s[2][qn][2], s[2][qn][3]));
      float a3 = fmaxf(fmaxf(s[3][qn][0], s[3][qn][1]), fmaxf(s[3][qn][2], s[3][qn][3]));
      pm[qn] = fmaxf(fmaxf(a0, a1), fmaxf(a2, a3));
    }
    if (!__all((pm[0] <= m[0] + 8.f) & (pm[1] <= m[1] + 8.f))) {  // rare, wave-uniform
      #pragma unroll
      for (int qn = 0; qn < 2; ++qn) {
        float tm = pm[qn];
        tm = fmaxf(tm, __shfl_xor(tm, 16));
        tm = fmaxf(tm, __shfl_xor(tm, 32));
        float mn = fmaxf(m[qn], tm);
        float a  = EXP2(m[qn] - mn);
        m[qn] = mn;
        lp[qn] *= a;
        #pragma unroll
        for (int mt = 0; mt < 4; ++mt)
          #pragma unroll
          for (int r = 0; r < 4; ++r)
            oacc[mt][qn][r] *= a;
      }
    }
    // --- exp2, per-lane l accumulation, pack to bf16 pairs ---
    unsigned int A[2][8];
    #pragma unroll
    for (int qn = 0; qn < 2; ++qn) {
      #pragma unroll
      for (int jt = 0; jt < 4; ++jt) {
        float p0 = EXP2(s[jt][qn][0] - m[qn]);
        float p1 = EXP2(s[jt][qn][1] - m[qn]);
        float p2 = EXP2(s[jt][qn][2] - m[qn]);
        float p3 = EXP2(s[jt][qn][3] - m[qn]);
        lp[qn] += (p0 + p1) + (p2 + p3);
        A[qn][2 * jt]     = cvtpk(p0, p1);
        A[qn][2 * jt + 1] = cvtpk(p2, p3);
      }
      // redistribute: word J (j-pair) moves lane-group (J>>1)&3 -> (J>>2)&3
      swap32(A[qn][0], A[qn][2]); swap32(A[qn][1], A[qn][3]);
      swap16(A[qn][0], A[qn][2]); swap16(A[qn][1], A[qn][3]);
      swap32(A[qn][4], A[qn][6]); swap32(A[qn][5], A[qn][7]);
      swap16(A[qn][4], A[qn][6]); swap16(A[qn][5], A[qn][7]);
    }
    vs8 pb[2][2];  // [qn][kj]: P[q=lr][j=kj*32+8lg+i] as B-fragment
    #pragma unroll
    for (int qn = 0; qn < 2; ++qn) {
      pb[qn][0] = __builtin_bit_cast(vs8, u32x4{A[qn][0], A[qn][1], A[qn][2], A[qn][3]});
      pb[qn][1] = __builtin_bit_cast(vs8, u32x4{A[qn][4], A[qn][5], A[qn][6], A[qn][7]});
    }
    // --- O^T += V^T P ---
    __builtin_amdgcn_s_setprio(1);
    #pragma unroll
    for (int kj = 0; kj < 2; ++kj) {
      #pragma unroll
      for (int mt = 0; mt < 4; ++mt) {
        vs8 vf = *(const vs8*)(sbv + (mt * 2 + kj) * 512 + lane * 8);
        oacc[mt][0] = MFMA(vf, pb[0][kj], oacc[mt][0]);
        oacc[mt][1] = MFMA(vf, pb[1][kj], oacc[mt][1]);
      }
    }
    __builtin_amdgcn_s_setprio(0);
    asm volatile("s_waitcnt vmcnt(0)");  // staged next-chunk loads have landed
    __syncthreads();
  }
  // --- epilogue: reduce l across lane groups, write O^T/l ---
  const int b = bh >> 3, h = bh & 7;
  float rl[2];
  #pragma unroll
  for (int qn = 0; qn < 2; ++qn) {
    float L = lp[qn];
    L += __shfl_xor(L, 16);
    L += __shfl_xor(L, 32);
    rl[qn] = 1.0f / L;
  }
  #pragma unroll
  for (int mt = 0; mt < 4; ++mt)
    #pragma unroll
    for (int qn = 0; qn < 2; ++qn)
      #pragma unroll
      for (int r = 0; r < 4; ++r) {
        int d = mt * 16 + lg * 4 + r;
        int q = qbase + qn * 16 + lr;
        ob[((size_t)(b * HID + h * 64 + d)) * NN + q] = f2bf(oacc[mt][qn][r] * rl[qn]);
      }
}

// ---------- K4: out projection y = w_out @ O + b ----------
__global__ __launch_bounds__(256) void k_out(const unsigned short* __restrict__ obuf,
    const unsigned short* __restrict__ wo, const float* __restrict__ bout,
    float* __restrict__ y) {
  __shared__ unsigned short os[64 * 136];
  const int bo = blockIdx.x & 3;
  const int bn = (blockIdx.x >> 2) & 63;
  const int b  = blockIdx.x >> 8;
  const int o0 = bo * 64, n0 = bn * 64;
  const int tid = threadIdx.x, wave = tid >> 6, lane = tid & 63, lr = lane & 15, lg = lane >> 4;
  const int orow = o0 + wave * 16;
  f4 acc[4] = { {0,0,0,0},{0,0,0,0},{0,0,0,0},{0,0,0,0} };
  for (int c0 = 0; c0 < HID; c0 += 128) {
    __syncthreads();
    {
      const int nl = tid & 63, cb = tid >> 6;
      const unsigned short* sp = obuf + ((size_t)b * HID + c0) * NN + n0 + nl;
      #pragma unroll 4
      for (int t = 0; t < 32; ++t) {
        int cc = cb * 32 + t;
        os[nl * 136 + cc] = sp[(size_t)cc * NN];
      }
    }
    __syncthreads();
    const unsigned short* wp = wo + (size_t)(orow + lr) * HID + c0 + lg * 8;
    #pragma unroll
    for (int cc0 = 0; cc0 < 128; cc0 += 32) {
      vs8 af = *(const vs8*)(wp + cc0);
      #pragma unroll
      for (int nc = 0; nc < 4; ++nc) {
        vs8 bf = *(const vs8*)(&os[(nc * 16 + lr) * 136 + cc0 + lg * 8]);
        acc[nc] = MFMA(af, bf, acc[nc]);
      }
    }
  }
  #pragma unroll
  for (int nc = 0; nc < 4; ++nc) {
    const int n = n0 + nc * 16 + lr;
    #pragma unroll
    for (int r = 0; r < 4; ++r)
      y[((size_t)b * C + orow + lg * 4 + r) * NN + n] = acc[nc][r] + bout[orow + lg * 4 + r];
  }
}

extern "C" void kernel_launch(void* const* d_in, const int* in_sizes, int n_in,
                              void* d_out, int out_size, void* d_ws, size_t ws_size,
                              hipStream_t stream) {
  const float* x    = (const float*)d_in[0];
  const float* g    = (const float*)d_in[1];
  const float* wqkv = (const float*)d_in[2];
  const float* wout = (const float*)d_in[3];
  const float* bout = (const float*)d_in[4];
  float* y = (float*)d_out;
  char* ws = (char*)d_ws;
  unsigned short* wg   = (unsigned short*)(ws);
  unsigned short* wo   = (unsigned short*)(ws + 786432);
  float*          invn = (float*)(ws + 1048576);
  unsigned short* qb   = (unsigned short*)(ws + 1081344);                // [bh][n][64]
  unsigned short* kb   = (unsigned short*)(ws + 1081344 + 8388608);      // [bh][n][64]
  unsigned short* vtb  = (unsigned short*)(ws + 1081344 + 2 * 8388608);  // [bh][64][n]
  unsigned short* obuf = (unsigned short*)(ws + 1081344 + 3 * 8388608);  // [b][512][n]
  k_prep<<<1536, 256, 0, stream>>>(wqkv, g, wout, wg, wo);
  k_norm<<<32, 256, 0, stream>>>(x, invn);
  k_qkv<<<1536, 256, 0, stream>>>(x, wg, invn, qb, kb, vtb);
  k_attn<<<512, 256, 0, stream>>>(qb, kb, vtb, obuf);
  k_out<<<512, 256, 0, stream>>>(obuf, wo, bout, y);
}